// Round 9
// baseline (813.426 us; speedup 1.0000x reference)
//
#include <hip/hip_runtime.h>
#include <math.h>

typedef __attribute__((ext_vector_type(8))) short bf16x8;
typedef __attribute__((ext_vector_type(4))) float f32x4;

// ---------------- helpers ----------------
__device__ __forceinline__ unsigned fkey_u(float v){
  unsigned b = __float_as_uint(v);
  return (b & 0x80000000u) ? ~b : (b | 0x80000000u);
}
__device__ __forceinline__ float fkey_inv(unsigned m){
  unsigned b = (m & 0x80000000u) ? (m & 0x7fffffffu) : ~m;
  return __uint_as_float(b);
}
__device__ __forceinline__ unsigned short f2bf(float f){
  unsigned u = __float_as_uint(f);
  unsigned r = (u + 0x7fffu + ((u>>16)&1u)) >> 16;
  return (unsigned short)r;
}
__device__ __forceinline__ unsigned long long shfl_xor_u64(unsigned long long v, int mask){
  int lo = __shfl_xor((int)(unsigned)(v & 0xFFFFFFFFull), mask, 64);
  int hi = __shfl_xor((int)(unsigned)(v >> 32), mask, 64);
  return ((unsigned long long)(unsigned)hi << 32) | (unsigned long long)(unsigned)lo;
}
#define BNI 0.9995003746877732f

// ---------------- register bitonic sort (descending), N = E*256, T=256 ----------------
template<int E, int J>
__device__ __forceinline__ void reg_step(unsigned long long* key, int t, int k2){
  #pragma unroll
  for (int r=0;r<E;r++){
    if ((r & J)==0){
      int e = t*E + r;
      bool desc = ((e & k2)==0);
      unsigned long long a=key[r], b=key[r^J];
      if (desc ? (a<b) : (a>b)){ key[r]=b; key[r^J]=a; }
    }
  }
}
template<int E>
__device__ __forceinline__ void reg_tail(unsigned long long* key, int t, int k2, int jstart){
  if constexpr (E>=8) { if (jstart>=4) reg_step<E,4>(key,t,k2); }
  if constexpr (E>=4) { if (jstart>=2) reg_step<E,2>(key,t,k2); }
  if (jstart>=1) reg_step<E,1>(key,t,k2);
}
template<int E>
__device__ void bitonic_desc(unsigned long long* key, unsigned long long* lds){
  const int t = threadIdx.x;
  const int N = E*256;
  for (int k2=2;k2<=N;k2<<=1){
    for (int j=k2>>1; j>=E; j>>=1){
      int w = j/E;
      bool lower = ((t & w)==0);
      bool desc  = (((t*E) & k2)==0);
      bool keep_max = (desc == lower);
      if (w < 64){
        #pragma unroll
        for (int r=0;r<E;r++){
          unsigned long long mine=key[r];
          unsigned long long o=shfl_xor_u64(mine, w);
          bool gt = mine > o;
          key[r] = keep_max ? (gt?mine:o) : (gt?o:mine);
        }
      } else {
        __syncthreads();
        #pragma unroll
        for (int r=0;r<E;r++) lds[t*E+r]=key[r];
        __syncthreads();
        #pragma unroll
        for (int r=0;r<E;r++){
          unsigned long long mine=key[r];
          unsigned long long o=lds[(t*E+r)^j];
          bool gt = mine > o;
          key[r] = keep_max ? (gt?mine:o) : (gt?o:mine);
        }
      }
    }
    int jstart = ((k2>>1) < (E>>1)) ? (k2>>1) : (E>>1);
    reg_tail<E>(key,t,k2,jstart);
  }
  __syncthreads();
  #pragma unroll
  for (int r=0;r<E;r++) lds[t*E+r]=key[r];
  __syncthreads();
}

// ---------------- S1: sort 1024-chunks, keep top-100 ----------------
__global__ __launch_bounds__(256) void k_sel1(
    const float* __restrict__ h0, const float* __restrict__ h1, const float* __restrict__ h2,
    unsigned long long* __restrict__ c1)
{
  int b = blockIdx.x;
  int layer, chunk;
  if (b < 320){ layer=0; chunk=b; }
  else if (b < 400){ layer=1; chunk=b-320; }
  else { layer=2; chunk=b-400; }
  const float* heat = (layer==0)?h0:((layer==1)?h1:h2);
  __shared__ unsigned long long lds[1024];
  unsigned long long key[4];
  int t = threadIdx.x;
  int base = chunk*1024 + t*4;
  float4 v = *(const float4*)(heat + base);
  key[0] = ((unsigned long long)fkey_u(v.x)<<32) | (unsigned long long)(0xFFFFFFFFu - (unsigned)(base+0));
  key[1] = ((unsigned long long)fkey_u(v.y)<<32) | (unsigned long long)(0xFFFFFFFFu - (unsigned)(base+1));
  key[2] = ((unsigned long long)fkey_u(v.z)<<32) | (unsigned long long)(0xFFFFFFFFu - (unsigned)(base+2));
  key[3] = ((unsigned long long)fkey_u(v.w)<<32) | (unsigned long long)(0xFFFFFFFFu - (unsigned)(base+3));
  bitonic_desc<4>(key, lds);
  if (t<100) c1[(size_t)b*100 + t] = lds[t];
}

// ---------------- S2: merge 20 sorted lists -> top-100 ----------------
__global__ __launch_bounds__(256) void k_sel2(
    const unsigned long long* __restrict__ c1, unsigned long long* __restrict__ c2)
{
  int b = blockIdx.x;
  __shared__ unsigned long long lds[2048];
  unsigned long long key[8];
  int t=threadIdx.x;
  const unsigned long long* src = c1 + (size_t)b*2000;
  #pragma unroll
  for (int r=0;r<8;r++){
    int i=t*8+r;
    key[r] = (i<2000)? src[i] : 0ull;
  }
  bitonic_desc<8>(key, lds);
  if (t<100) c2[(size_t)b*100+t]=lds[t];
}

// ---------------- S3: final merge per layer + decode ----------------
__global__ __launch_bounds__(256) void k_sel3_decode(
    const unsigned long long* __restrict__ c2,
    const float* __restrict__ tl0,const float* __restrict__ tl1,const float* __restrict__ tl2,
    const float* __restrict__ br0,const float* __restrict__ br1,const float* __restrict__ br2,
    float* __restrict__ dets, float* __restrict__ bws, float* __restrict__ mbw)
{
  int layer = blockIdx.x;
  int hw = 4096 >> (layer*2);
  int W = 64>>layer;
  float Wf = (float)W;
  const float* tl = (layer==0)?tl0:((layer==1)?tl1:tl2);
  const float* br = (layer==0)?br0:((layer==1)?br1:br2);
  int base = (layer==0)?0:((layer==1)?1600:2000);
  int cnt  = (layer==0)?1600:((layer==1)?400:100);
  __shared__ unsigned long long lds[2048];
  __shared__ float scl[100];
  unsigned long long key[8];
  int t = threadIdx.x;
  #pragma unroll
  for (int r=0;r<8;r++){
    int i=t*8+r;
    key[r] = (i<cnt)? c2[base+i] : 0ull;
  }
  bitonic_desc<8>(key, lds);
  unsigned long long kwin=0;
  if (t<100) kwin = lds[t];
  float tlx=0,tly=0,brx=0,bry=0,xs=0,ys=0,clsfv=0,scv=0;
  if (t<100){
    unsigned m=(unsigned)(kwin>>32);
    unsigned gidx = 0xFFFFFFFFu - (unsigned)(kwin & 0xFFFFFFFFull);
    float val = fkey_inv(m);
    int cls = (int)(gidx / (unsigned)hw);
    int rem = (int)(gidx % (unsigned)hw);
    int iy = rem / W, ix = rem % W;
    xs = (float)ix; ys = (float)iy; clsfv = (float)cls;
    float t0=tl[rem], t1=tl[hw+rem], b0=br[rem], b1=br[hw+rem];
    tlx = fminf(fmaxf(xs - (3.0f*t0 + 2.5f), 0.0f), Wf);
    tly = fminf(fmaxf(ys - (3.0f*t1 + 2.5f), 0.0f), Wf);
    brx = fminf(fmaxf(xs + (3.0f*b0 + 2.5f), 0.0f), Wf);
    bry = fminf(fmaxf(ys + (3.0f*b1 + 2.5f), 0.0f), Wf);
    scv = ((brx<tlx)||(bry<tly)) ? -1.0f : val;
    scl[t]=scv;
  }
  __syncthreads();
  if (t<100){
    int rank=0;
    for (int i=0;i<100;i++){
      float si=scl[i];
      rank += ((si>scv)||(si==scv && i<t)) ? 1 : 0;
    }
    int row = layer*100 + rank;
    float sx = (float)(1<<layer);
    float* dr = dets + row*8;
    dr[0]=tlx*sx; dr[1]=tly*sx; dr[2]=brx*sx; dr[3]=bry*sx;
    dr[4]=scv; dr[5]=scv; dr[6]=(float)layer; dr[7]=clsfv;
    float* bwr = bws + row*8;
    bwr[0]=tlx;bwr[1]=tly;bwr[2]=brx;bwr[3]=bry;bwr[4]=scv;bwr[5]=scv;bwr[6]=(float)layer;bwr[7]=clsfv;
    float* mr = mbw + row*5;
    mr[0]=xs-4.0f; mr[1]=ys-4.0f; mr[2]=xs+4.0f; mr[3]=ys+4.0f; mr[4]=(float)layer;
  }
}

// ---------------- K_C: NMS — rank-space masks + single-thread register scan ----------------
#define SCAN_GROUP(SW, BASE, CNT) \
  _Pragma("unroll 4") \
  for (int rr=0; rr<CNT; rr++){ \
    int r = BASE+rr; \
    unsigned long long w0=sm[r][0],w1=sm[r][1],w2=sm[r][2],w3=sm[r][3],w4=sm[r][4]; \
    unsigned long long kq = (~(SW>>rr))&1ull; \
    keepr[r]=(unsigned char)kq; \
    unsigned long long msk = 0ull - kq; \
    s0|=w0&msk; s1|=w1&msk; s2|=w2&msk; s3|=w3&msk; s4|=w4&msk; \
  }

__global__ __launch_bounds__(320) void k_nms(
    const float* __restrict__ dets, const float* __restrict__ bws, const float* __restrict__ mbw,
    float* __restrict__ out_dets, float* __restrict__ mbf, int* __restrict__ clsf,
    int* __restrict__ layf, float* __restrict__ nbox)
{
  __shared__ __align__(16) float4 rb[300];
  __shared__ float rs[300];
  __shared__ int orig[300];
  __shared__ __align__(16) float sc[300];
  __shared__ __align__(16) float kk[300];
  __shared__ __align__(16) float lq[300];
  __shared__ float lyv[300];
  __shared__ unsigned long long sm[300][5];
  __shared__ unsigned char keepr[304];
  __shared__ int sel_[300], fperm[300];
  int t = threadIdx.x;
  float X1=0,Y1=0,X2=0,Y2=0,S=0;
  if (t<300){
    const float* r = dets + t*8;
    X1=r[1];Y1=r[2];X2=r[3];Y2=r[4];
    S=r[4];
    sc[t]=S;
    lyv[t]=mbw[t*5+4];
  }
  __syncthreads();
  if (t<300){
    int rank=0;
    for (int j4=0;j4<75;j4++){
      float4 s4=*(const float4*)&sc[j4*4];
      int j=j4*4;
      rank += ((s4.x>S)||(s4.x==S&&(j+0)<t)) ? 1:0;
      rank += ((s4.y>S)||(s4.y==S&&(j+1)<t)) ? 1:0;
      rank += ((s4.z>S)||(s4.z==S&&(j+2)<t)) ? 1:0;
      rank += ((s4.w>S)||(s4.w==S&&(j+3)<t)) ? 1:0;
    }
    rb[rank]=make_float4(X1,Y1,X2,Y2);
    rs[rank]=S;
    orig[rank]=t;
  }
  __syncthreads();
  if (t<300){
    float4 me=rb[t];
    float A=(me.z-me.x)*(me.w-me.y);
    #pragma unroll
    for (int jw=0;jw<5;jw++){
      unsigned long long bits=0;
      int lim=(jw==4)?44:64;
      for (int jj=0;jj<lim;jj++){
        int j=jw*64+jj;
        float4 q=rb[j];
        float aj=(q.z-q.x)*(q.w-q.y);
        float ix1=fmaxf(me.x,q.x), iy1=fmaxf(me.y,q.y);
        float ix2=fminf(me.z,q.z), iy2=fminf(me.w,q.w);
        float it=fmaxf(ix2-ix1,0.f)*fmaxf(iy2-iy1,0.f);
        float iou=it/(A+aj-it+1e-9f);
        bits |= ((unsigned long long)(iou>0.5f))<<jj;
      }
      sm[t][jw]=bits;
    }
  }
  __syncthreads();
  if (t==0){
    unsigned long long s0=0,s1=0,s2=0,s3=0,s4=0;
    SCAN_GROUP(s0,0,64)
    SCAN_GROUP(s1,64,64)
    SCAN_GROUP(s2,128,64)
    SCAN_GROUP(s3,192,64)
    SCAN_GROUP(s4,256,44)
  }
  __syncthreads();
  if (t<300) kk[orig[t]] = keepr[t] ? rs[t] : -1000000000.0f;
  __syncthreads();
  float KV=0; int rank2=0;
  if (t<300){
    KV=kk[t];
    for (int j4=0;j4<75;j4++){
      float4 s4=*(const float4*)&kk[j4*4];
      int j=j4*4;
      rank2 += ((s4.x>KV)||(s4.x==KV&&(j+0)<t)) ? 1:0;
      rank2 += ((s4.y>KV)||(s4.y==KV&&(j+1)<t)) ? 1:0;
      rank2 += ((s4.z>KV)||(s4.z==KV&&(j+2)<t)) ? 1:0;
      rank2 += ((s4.w>KV)||(s4.w==KV&&(j+3)<t)) ? 1:0;
    }
    sel_[rank2]=t;
  }
  __syncthreads();
  if (t<300) lq[t]=lyv[sel_[t]];
  __syncthreads();
  if (t<300){
    float L=lq[t]; int rank3=0;
    for (int j4=0;j4<75;j4++){
      float4 s4=*(const float4*)&lq[j4*4];
      int j=j4*4;
      rank3 += ((s4.x>L)||(s4.x==L&&(j+0)<t)) ? 1:0;
      rank3 += ((s4.y>L)||(s4.y==L&&(j+1)<t)) ? 1:0;
      rank3 += ((s4.z>L)||(s4.z==L&&(j+2)<t)) ? 1:0;
      rank3 += ((s4.w>L)||(s4.w==L&&(j+3)<t)) ? 1:0;
    }
    fperm[rank3]=sel_[t];
  }
  __syncthreads();
  if (t<300){
    int src=fperm[t];
    const float* dr=dets+src*8;
    #pragma unroll
    for (int c=0;c<8;c++) out_dets[t*8+c]=dr[c];
    const float* mr=mbw+src*5;
    #pragma unroll
    for (int c=0;c<5;c++) mbf[t*5+c]=mr[c];
    int cc=(int)dr[7]; cc = cc<0?0:(cc>79?79:cc); clsf[t]=cc;
    int lv=(int)mr[4]; lv = lv<0?0:(lv>2?2:lv); layf[t]=lv;
    const float* bw=bws+src*8;
    nbox[t*4+0]=4.375f*(bw[0]-mr[0]);
    nbox[t*4+1]=4.375f*(bw[1]-mr[1]);
    nbox[t*4+2]=4.375f*(bw[2]-mr[0]);
    nbox[t*4+3]=4.375f*(bw[3]-mr[1]);
  }
}

// ---------------- ROI align -> bf16 [px][ci] ----------------
__global__ __launch_bounds__(256) void k_roi(
    const float* __restrict__ f0,const float* __restrict__ f1,const float* __restrict__ f2,
    const float* __restrict__ mbf, const int* __restrict__ layf,
    unsigned short* __restrict__ rois, int r0)
{
  int nl = blockIdx.x; int g = r0 + nl;
  __shared__ int ix0[9], ix1[9], iy0[9], iy1[9];
  __shared__ float wx[9], wy[9];
  int lay = layf[g];
  int W = 64>>lay;
  float Wf1 = (float)(W-1);
  const float* feat = (lay==0)?f0:((lay==1)?f1:f2);
  int t=threadIdx.x;
  if (t<9){
    float x1=mbf[g*5+0], x2=mbf[g*5+2];
    float jx = ((float)t + 0.5f)/9.0f;
    float gx = x1 + (x2-x1)*jx;
    float xx = fminf(fmaxf(gx,0.0f), Wf1);
    float x0f = floorf(xx);
    wx[t]=xx-x0f;
    int x0=(int)x0f; ix0[t]=x0; ix1[t]=min(x0+1,W-1);
  } else if (t>=16 && t<25){
    int j=t-16;
    float y1=mbf[g*5+1], y2=mbf[g*5+3];
    float jy=((float)j+0.5f)/9.0f;
    float gy=y1+(y2-y1)*jy;
    float yy=fminf(fmaxf(gy,0.0f),Wf1);
    float y0f=floorf(yy);
    wy[j]=yy-y0f;
    int y0=(int)y0f; iy0[j]=y0; iy1[j]=min(y0+1,W-1);
  }
  __syncthreads();
  int c=t;
  const float* fp = feat + (size_t)c*W*W;
  unsigned short* op = rois + (size_t)nl*81*256;
  for (int p=0;p<81;p++){
    int py=p/9, px=p%9;
    float v00=fp[iy0[py]*W+ix0[px]];
    float v01=fp[iy0[py]*W+ix1[px]];
    float v10=fp[iy1[py]*W+ix0[px]];
    float v11=fp[iy1[py]*W+ix1[px]];
    float wxx=wx[px], wyy=wy[py];
    float v = (1.0f-wyy)*((1.0f-wxx)*v00 + wxx*v01) + wyy*((1.0f-wxx)*v10 + wxx*v11);
    op[(size_t)p*256 + c] = f2bf(v);
  }
}

// ---------------- weight prep ----------------
__global__ __launch_bounds__(64) void k_wprep3(
    const float* __restrict__ c1w, const float* __restrict__ midw, const float* __restrict__ c5w,
    unsigned short* __restrict__ WB)
{
  int b = blockIdx.x, c = blockIdx.y, l = threadIdx.x;
  int t = b>>7;
  const float* src = (c==0)? c1w : (c<=3 ? midw + (size_t)(c-1)*589824 : c5w);
  unsigned short* dst = WB + (size_t)c*589824 + ((size_t)b<<9) + l*8;
  int co = (b&15)*16 + (l&15);
  int cib = ((b>>4)&7)*32 + ((l>>4)<<3);
  #pragma unroll
  for (int j=0;j<8;j++) dst[j] = f2bf(src[((size_t)co*256 + cib + j)*9 + t]);
}
__global__ __launch_bounds__(64) void k_wprep2(
    const float* __restrict__ d1w, const float* __restrict__ d2w,
    unsigned short* __restrict__ WD)
{
  int b = blockIdx.x, c = blockIdx.y, l = threadIdx.x;
  int t = b>>7;
  const float* src = (c==0)? d1w : d2w;
  unsigned short* dst = WD + (size_t)c*262144 + ((size_t)b<<9) + l*8;
  int co = (b&15)*16 + (l&15);
  int cib = ((b>>4)&7)*32 + ((l>>4)<<3);
  #pragma unroll
  for (int j=0;j<8;j++) dst[j] = f2bf(src[((size_t)co*256 + cib + j)*4 + t]);
}

// ---------------- MFMA conv3x3 @ 9x9, M-split halves ----------------
__global__ __launch_bounds__(256,3) void k_mconv9h(
    const unsigned short* __restrict__ Xg, unsigned short* __restrict__ Yg,
    const unsigned short* __restrict__ WBc,
    const float* __restrict__ Bc, const float* __restrict__ Gg, const float* __restrict__ Bn)
{
  __shared__ __align__(16) unsigned short Xp[88*264];
  int tid=threadIdx.x, l=tid&63, w=tid>>6;
  int h=blockIdx.y;
  int rlo = h ? 4 : -1;
  const unsigned short* Xr = Xg + (size_t)blockIdx.x*81*256;
  for (int idx=tid; idx<88*32; idx+=256){
    int pp=idx>>5, k8=idx&31;
    int y=pp/11 + rlo, x=pp%11 - 1;
    uint4 v{0,0,0,0};
    if ((unsigned)y<9u && (unsigned)x<9u) v = *(const uint4*)(Xr + ((y*9+x)<<8) + (k8<<3));
    *(uint4*)&Xp[pp*264 + (k8<<3)] = v;
  }
  __syncthreads();
  int mbase = h*48;
  int pixb[3];
  #pragma unroll
  for (int mt=0;mt<3;mt++){
    int m=mbase+mt*16+(l&15); if(m>80)m=80;
    pixb[mt]=(m/9 - rlo)*11 + (m%9) + 1;
  }
  int kg=(l>>4)<<3;
  f32x4 acc[3][4] = {};
  const unsigned short* wbase = WBc + (size_t)l*8;
  for (int t9=0;t9<9;t9++){
    int toff=(t9/3-1)*11 + (t9%3-1);
    for (int kc=0;kc<8;kc++){
      bf16x8 a[3], b[4];
      #pragma unroll
      for (int mt=0;mt<3;mt++) a[mt] = *(const bf16x8*)&Xp[(pixb[mt]+toff)*264 + (kc<<5) + kg];
      #pragma unroll
      for (int nn=0;nn<4;nn++) b[nn] = *(const bf16x8*)(wbase + ((size_t)(((t9<<3)+kc)*16 + (w<<2)+nn)<<9));
      #pragma unroll
      for (int mt=0;mt<3;mt++){
        #pragma unroll
        for (int nn=0;nn<4;nn++)
          acc[mt][nn] = __builtin_amdgcn_mfma_f32_16x16x32_bf16(a[mt], b[nn], acc[mt][nn], 0,0,0);
      }
    }
  }
  unsigned short* Yr = Yg + (size_t)blockIdx.x*81*256;
  int rb=(l>>4)<<2;
  #pragma unroll
  for (int nn=0;nn<4;nn++){
    int co=(w<<6)+(nn<<4)+(l&15);
    float bc=Bc[co], gm=Gg[co]*BNI, bb=Bn[co];
    #pragma unroll
    for (int mt=0;mt<3;mt++){
      #pragma unroll
      for (int r=0;r<4;r++){
        int m=mbase+mt*16+rb+r;
        if (m<81){
          float v=fmaxf((acc[mt][nn][r]+bc)*gm+bb, 0.f);
          Yr[m*256+co]=f2bf(v);
        }
      }
    }
  }
}

// ---------------- MFMA deconv1 (9->18), all 4 taps in one block ----------------
__global__ __launch_bounds__(256,3) void k_mdeconv1(
    const unsigned short* __restrict__ Xg, unsigned short* __restrict__ Yg,
    const unsigned short* __restrict__ WD1, const float* __restrict__ Bd)
{
  __shared__ __align__(16) unsigned short Xp[81*264];
  int tid=threadIdx.x, l=tid&63, w=tid>>6;
  const unsigned short* Xr = Xg + (size_t)blockIdx.x*81*256;
  for (int idx=tid; idx<81*32; idx+=256){
    int pp=idx>>5, k8=idx&31;
    *(uint4*)&Xp[pp*264+(k8<<3)] = *(const uint4*)(Xr + (pp<<8)+(k8<<3));
  }
  __syncthreads();
  int pixb[6];
  #pragma unroll
  for (int mt=0;mt<6;mt++){ int m=mt*16+(l&15); pixb[mt]=(m>80)?80:m; }
  int kg=(l>>4)<<3;
  int rb=(l>>4)<<2;
  unsigned short* Yr = Yg + (size_t)blockIdx.x*324*256;
  for (int tp=0;tp<4;tp++){
    f32x4 acc[6][4] = {};
    const unsigned short* wbase = WD1 + (size_t)tp*65536 + (size_t)l*8;
    for (int kc=0;kc<8;kc++){
      bf16x8 a[6], b[4];
      #pragma unroll
      for (int mt=0;mt<6;mt++) a[mt] = *(const bf16x8*)&Xp[pixb[mt]*264 + (kc<<5) + kg];
      #pragma unroll
      for (int nn=0;nn<4;nn++) b[nn] = *(const bf16x8*)(wbase + ((size_t)(kc*16 + (w<<2)+nn)<<9));
      #pragma unroll
      for (int mt=0;mt<6;mt++){
        #pragma unroll
        for (int nn=0;nn<4;nn++)
          acc[mt][nn] = __builtin_amdgcn_mfma_f32_16x16x32_bf16(a[mt], b[nn], acc[mt][nn], 0,0,0);
      }
    }
    int ky=tp>>1, kx=tp&1;
    #pragma unroll
    for (int nn=0;nn<4;nn++){
      int co=(w<<6)+(nn<<4)+(l&15);
      float bd=Bd[co];
      #pragma unroll
      for (int mt=0;mt<6;mt++){
        #pragma unroll
        for (int r=0;r<4;r++){
          int m=mt*16+rb+r;
          if (m<81){
            int iy=m/9, ix=m%9;
            int opx=(2*iy+1-ky)*18 + (2*ix+1-kx);
            Yr[opx*256+co]=f2bf(fmaxf(acc[mt][nn][r]+bd,0.f));
          }
        }
      }
    }
  }
}

// ---------------- MFMA conv3x3 @ 18x18 + bias + BN + ReLU (nn=4, linear LDS) ---------
__global__ __launch_bounds__(256,3) void k_mconv18(
    const unsigned short* __restrict__ Xg, unsigned short* __restrict__ Yg,
    const unsigned short* __restrict__ WBc,
    const float* __restrict__ Bc, const float* __restrict__ Gg, const float* __restrict__ Bn)
{
  __shared__ __align__(16) unsigned short Xp[160*136];
  int tid=threadIdx.x, l=tid&63, w=tid>>6;
  int rg=blockIdx.y;
  const unsigned short* Xr = Xg + (size_t)blockIdx.x*324*256;
  int pixb[7];
  #pragma unroll
  for (int mt=0;mt<7;mt++){ int m=mt*16+(l&15); if(m>107)m=107; pixb[mt]=(m/18)*20+(m%18); }
  int kg=(l>>4)<<3;
  f32x4 acc[7][4] = {};
  const unsigned short* wbase = WBc + (size_t)l*8;
  for (int h=0;h<2;h++){
    __syncthreads();
    for (int idx=tid; idx<160*16; idx+=256){
      int pp=idx>>4, k8=idx&15;
      int py=rg*6-1+pp/20, px=pp%20-1;
      uint4 v{0,0,0,0};
      if ((unsigned)py<18u && (unsigned)px<18u)
        v = *(const uint4*)(Xr + ((py*18+px)<<8) + (h<<7) + (k8<<3));
      *(uint4*)&Xp[pp*136 + (k8<<3)] = v;
    }
    __syncthreads();
    for (int t9=0;t9<9;t9++){
      int toff=(t9/3)*20 + (t9%3);
      for (int kc=0;kc<4;kc++){
        int kcg=(h<<2)+kc;
        bf16x8 a[7], b[4];
        #pragma unroll
        for (int mt=0;mt<7;mt++) a[mt] = *(const bf16x8*)&Xp[(pixb[mt]+toff)*136 + (kc<<5) + kg];
        #pragma unroll
        for (int nn=0;nn<4;nn++) b[nn] = *(const bf16x8*)(wbase + ((size_t)(((t9<<3)+kcg)*16 + (w<<2)+nn)<<9));
        #pragma unroll
        for (int mt=0;mt<7;mt++){
          #pragma unroll
          for (int nn=0;nn<4;nn++)
            acc[mt][nn] = __builtin_amdgcn_mfma_f32_16x16x32_bf16(a[mt], b[nn], acc[mt][nn], 0,0,0);
        }
      }
    }
  }
  unsigned short* Yr = Yg + (size_t)blockIdx.x*324*256;
  int rb=(l>>4)<<2;
  #pragma unroll
  for (int nn=0;nn<4;nn++){
    int co=(w<<6)+(nn<<4)+(l&15);
    float bc=Bc[co], gm=Gg[co]*BNI, bb=Bn[co];
    #pragma unroll
    for (int mt=0;mt<7;mt++){
      #pragma unroll
      for (int r=0;r<4;r++){
        int m=mt*16+rb+r;
        if (m<108){
          int opx=rg*108+m;
          Yr[opx*256+co]=f2bf(fmaxf((acc[mt][nn][r]+bc)*gm+bb, 0.f));
        }
      }
    }
  }
}

// ---------------- MFMA deconv2 (18->36) + ReLU + c6[cls] + sigmoid, 4 taps/block --------
__global__ __launch_bounds__(256,2) void k_mdec2c6(
    const unsigned short* __restrict__ Xg,
    const unsigned short* __restrict__ WD2, const float* __restrict__ Bd,
    const float* __restrict__ W6, const float* __restrict__ B6,
    const int* __restrict__ clsf, float* __restrict__ mask36, int r0)
{
  __shared__ __align__(16) unsigned short Xp[108*264];
  __shared__ float part[4][112];
  int tid=threadIdx.x, l=tid&63, w=tid>>6;
  int rg=blockIdx.y;
  int g=r0+blockIdx.x;
  const unsigned short* Xr = Xg + (size_t)blockIdx.x*324*256 + (size_t)rg*108*256;
  for (int idx=tid; idx<108*32; idx+=256){
    int pp=idx>>5, k8=idx&31;
    *(uint4*)&Xp[pp*264+(k8<<3)] = *(const uint4*)(Xr + (pp<<8)+(k8<<3));
  }
  __syncthreads();
  int pixb[7];
  #pragma unroll
  for (int mt=0;mt<7;mt++){ int m=mt*16+(l&15); pixb[mt]=(m>107)?107:m; }
  int kg=(l>>4)<<3;
  int rb=(l>>4)<<2;
  int cls=clsf[g];
  float w6v[4], bdv[4];
  #pragma unroll
  for (int nn=0;nn<4;nn++){
    int co=(w<<6)+(nn<<4)+(l&15);
    w6v[nn]=W6[(size_t)cls*256+co];
    bdv[nn]=Bd[co];
  }
  float b6c=B6[cls];
  for (int tp=0;tp<4;tp++){
    f32x4 acc[7][4] = {};
    const unsigned short* wbase = WD2 + (size_t)tp*65536 + (size_t)l*8;
    for (int kc=0;kc<8;kc++){
      bf16x8 a[7], b[4];
      #pragma unroll
      for (int mt=0;mt<7;mt++) a[mt] = *(const bf16x8*)&Xp[pixb[mt]*264 + (kc<<5) + kg];
      #pragma unroll
      for (int nn=0;nn<4;nn++) b[nn] = *(const bf16x8*)(wbase + ((size_t)(kc*16 + (w<<2)+nn)<<9));
      #pragma unroll
      for (int mt=0;mt<7;mt++){
        #pragma unroll
        for (int nn=0;nn<4;nn++)
          acc[mt][nn] = __builtin_amdgcn_mfma_f32_16x16x32_bf16(a[mt], b[nn], acc[mt][nn], 0,0,0);
      }
    }
    #pragma unroll
    for (int mt=0;mt<7;mt++){
      float s0=0.f,s1=0.f,s2=0.f,s3=0.f;
      #pragma unroll
      for (int nn=0;nn<4;nn++){
        s0 += fmaxf(acc[mt][nn][0]+bdv[nn],0.f)*w6v[nn];
        s1 += fmaxf(acc[mt][nn][1]+bdv[nn],0.f)*w6v[nn];
        s2 += fmaxf(acc[mt][nn][2]+bdv[nn],0.f)*w6v[nn];
        s3 += fmaxf(acc[mt][nn][3]+bdv[nn],0.f)*w6v[nn];
      }
      #pragma unroll
      for (int o=1;o<16;o<<=1){
        s0 += __shfl_xor(s0,o,64);
        s1 += __shfl_xor(s1,o,64);
        s2 += __shfl_xor(s2,o,64);
        s3 += __shfl_xor(s3,o,64);
      }
      if ((l&15)==0){
        int mb=mt*16+rb;
        part[w][mb+0]=s0; part[w][mb+1]=s1; part[w][mb+2]=s2; part[w][mb+3]=s3;
      }
    }
    __syncthreads();
    if (tid<108){
      float lg = part[0][tid]+part[1][tid]+part[2][tid]+part[3][tid] + b6c;
      int pg=rg*108+tid, iy=pg/18, ix=pg%18;
      int ky=tp>>1, kx=tp&1;
      mask36[(size_t)g*1296 + (2*iy+1-ky)*36 + (2*ix+1-kx)] = 1.0f/(1.0f+expf(-lg));
    }
    __syncthreads();
  }
}

// ---------------- crop_resize 36x36 -> 36x36 ----------------
__global__ __launch_bounds__(256) void k_crop(
    const float* __restrict__ mask36, const float* __restrict__ nbox,
    float* __restrict__ outm)
{
  int r=blockIdx.x;
  __shared__ float m[1296];
  int t=threadIdx.x;
  for (int i=t;i<1296;i+=256) m[i]=mask36[(size_t)r*1296+i];
  float x1=nbox[r*4+0], y1=nbox[r*4+1], x2=nbox[r*4+2], y2=nbox[r*4+3];
  __syncthreads();
  for (int p=t;p<1296;p+=256){
    int oy=p/36, ox=p%36;
    float tx=(float)ox/35.0f, ty=(float)oy/35.0f;
    float gx=x1+(x2-x1)*tx, gy=y1+(y2-y1)*ty;
    float xx=fminf(fmaxf(gx,0.f),35.0f), yy=fminf(fmaxf(gy,0.f),35.0f);
    float x0f=floorf(xx), y0f=floorf(yy);
    float wxv=xx-x0f, wyv=yy-y0f;
    int x0=(int)x0f, y0=(int)y0f;
    int x1i=min(x0+1,35), y1i=min(y0+1,35);
    float v00=m[y0*36+x0], v01=m[y0*36+x1i], v10=m[y1i*36+x0], v11=m[y1i*36+x1i];
    outm[(size_t)r*1296+p]=(1.f-wyv)*((1.f-wxv)*v00+wxv*v01)+wyv*((1.f-wxv)*v10+wxv*v11);
  }
}

// ---------------- host ----------------
extern "C" void kernel_launch(void* const* d_in, const int* in_sizes, int n_in,
                              void* d_out, int out_size, void* d_ws, size_t ws_size,
                              hipStream_t stream) {
  int iH[3], iT[3], iB[3], iF[3];
  if (n_in >= 12 && in_sizes[1] == 2*64*64) {
    for (int l=0;l<3;l++){ iH[l]=l*4+0; iT[l]=l*4+1; iB[l]=l*4+2; iF[l]=l*4+3; }
  } else {
    for (int l=0;l<3;l++){ iH[l]=l; iT[l]=3+l; iB[l]=6+l; iF[l]=9+l; }
  }
  const float* heat0=(const float*)d_in[iH[0]];
  const float* heat1=(const float*)d_in[iH[1]];
  const float* heat2=(const float*)d_in[iH[2]];
  const float* tl0=(const float*)d_in[iT[0]];
  const float* tl1=(const float*)d_in[iT[1]];
  const float* tl2=(const float*)d_in[iT[2]];
  const float* br0=(const float*)d_in[iB[0]];
  const float* br1=(const float*)d_in[iB[1]];
  const float* br2=(const float*)d_in[iB[2]];
  const float* feat0=(const float*)d_in[iF[0]];
  const float* feat1=(const float*)d_in[iF[1]];
  const float* feat2=(const float*)d_in[iF[2]];
  const float* c1w=(const float*)d_in[12];
  const float* c1b=(const float*)d_in[13];
  const float* midw=(const float*)d_in[14];
  const float* midb=(const float*)d_in[15];
  const float* bng=(const float*)d_in[16];
  const float* bnb=(const float*)d_in[17];
  const float* d1w=(const float*)d_in[18];
  const float* d1b=(const float*)d_in[19];
  const float* d2w=(const float*)d_in[20];
  const float* d2b=(const float*)d_in[21];
  const float* c5w=(const float*)d_in[22];
  const float* c5b=(const float*)d_in[23];
  const float* c6w=(const float*)d_in[24];
  const float* c6b=(const float*)d_in[25];
  float* out=(float*)d_out;

  char* ws=(char*)d_ws;
  size_t cur=0;
  auto alloc=[&](size_t bytes)->char*{
    char* p=ws+cur;
    cur=(cur+bytes+255)&~(size_t)255;
    return p;
  };
  unsigned short* WB=(unsigned short*)alloc(5ull*589824*2);
  unsigned short* WD=(unsigned short*)alloc(2ull*262144*2);
  unsigned long long* c1s=(unsigned long long*)alloc(420ull*100*8);
  unsigned long long* c2s=(unsigned long long*)alloc(21ull*100*8);
  float* detsw=(float*)alloc(300*8*4);
  float* bwsw=(float*)alloc(300*8*4);
  float* mbw=(float*)alloc(300*5*4);
  float* mbf=(float*)alloc(300*5*4);
  int* clsf=(int*)alloc(300*4);
  int* layf=(int*)alloc(300*4);
  float* nbox=(float*)alloc(300*4*4);
  float* mask36=(float*)alloc(300ull*1296*4);
  size_t fixed=cur;
  size_t perroi = (size_t)(2*81 + 2*324)*256*2;
  size_t avail = (ws_size>fixed+4096)? (ws_size-fixed-4096):0;
  int NRC = (int)(avail/perroi);
  if (NRC>300) NRC=300;
  if (NRC<1) NRC=1;
  unsigned short* X0 =(unsigned short*)alloc((size_t)NRC*81*256*2);
  unsigned short* B9 =(unsigned short*)alloc((size_t)NRC*81*256*2);
  unsigned short* C18=(unsigned short*)alloc((size_t)NRC*324*256*2);
  unsigned short* D18=(unsigned short*)alloc((size_t)NRC*324*256*2);

  k_wprep3<<<dim3(1152,5),dim3(64),0,stream>>>(c1w,midw,c5w,WB);
  k_wprep2<<<dim3(512,2),dim3(64),0,stream>>>(d1w,d2w,WD);

  k_sel1<<<dim3(420),dim3(256),0,stream>>>(heat0,heat1,heat2,c1s);
  k_sel2<<<dim3(21),dim3(256),0,stream>>>(c1s,c2s);
  k_sel3_decode<<<dim3(3),dim3(256),0,stream>>>(c2s,tl0,tl1,tl2,br0,br1,br2,detsw,bwsw,mbw);
  k_nms<<<dim3(1),dim3(320),0,stream>>>(detsw,bwsw,mbw,out,mbf,clsf,layf,nbox);

  for (int r0=0;r0<300;r0+=NRC){
    int nr = (300-r0 < NRC)? (300-r0) : NRC;
    k_roi<<<dim3(nr),dim3(256),0,stream>>>(feat0,feat1,feat2,mbf,layf,X0,r0);
    k_mconv9h<<<dim3(nr,2),dim3(256),0,stream>>>(X0,B9,WB,               c1b,       bng,      bnb);
    k_mconv9h<<<dim3(nr,2),dim3(256),0,stream>>>(B9,X0,WB+1ull*589824,   midb,      bng+256,  bnb+256);
    k_mconv9h<<<dim3(nr,2),dim3(256),0,stream>>>(X0,B9,WB+2ull*589824,   midb+256,  bng+512,  bnb+512);
    k_mconv9h<<<dim3(nr,2),dim3(256),0,stream>>>(B9,X0,WB+3ull*589824,   midb+512,  bng+768,  bnb+768);
    k_mdeconv1<<<dim3(nr),dim3(256),0,stream>>>(X0,C18,WD,d1b);
    k_mconv18<<<dim3(nr,3),dim3(256),0,stream>>>(C18,D18,WB+4ull*589824, c5b, bng+1024, bnb+1024);
    k_mdec2c6<<<dim3(nr,3),dim3(256),0,stream>>>(D18,WD+262144,d2b,c6w,c6b,clsf,mask36,r0);
  }
  k_crop<<<dim3(300),dim3(256),0,stream>>>(mask36,nbox,out+2400);
}

// Round 10
// 641.284 us; speedup vs baseline: 1.2684x; 1.2684x over previous
//
#include <hip/hip_runtime.h>
#include <math.h>

typedef __attribute__((ext_vector_type(8))) short bf16x8;
typedef __attribute__((ext_vector_type(4))) float f32x4;

// ---------------- helpers ----------------
__device__ __forceinline__ unsigned fkey_u(float v){
  unsigned b = __float_as_uint(v);
  return (b & 0x80000000u) ? ~b : (b | 0x80000000u);
}
__device__ __forceinline__ float fkey_inv(unsigned m){
  unsigned b = (m & 0x80000000u) ? (m & 0x7fffffffu) : ~m;
  return __uint_as_float(b);
}
__device__ __forceinline__ unsigned short f2bf(float f){
  unsigned u = __float_as_uint(f);
  unsigned r = (u + 0x7fffu + ((u>>16)&1u)) >> 16;
  return (unsigned short)r;
}
__device__ __forceinline__ unsigned long long shfl_xor_u64(unsigned long long v, int mask){
  int lo = __shfl_xor((int)(unsigned)(v & 0xFFFFFFFFull), mask, 64);
  int hi = __shfl_xor((int)(unsigned)(v >> 32), mask, 64);
  return ((unsigned long long)(unsigned)hi << 32) | (unsigned long long)(unsigned)lo;
}
#define BNI 0.9995003746877732f

// ---------------- register bitonic sort (descending), N = E*256, T=256 ----------------
template<int E, int J>
__device__ __forceinline__ void reg_step(unsigned long long* key, int t, int k2){
  #pragma unroll
  for (int r=0;r<E;r++){
    if ((r & J)==0){
      int e = t*E + r;
      bool desc = ((e & k2)==0);
      unsigned long long a=key[r], b=key[r^J];
      if (desc ? (a<b) : (a>b)){ key[r]=b; key[r^J]=a; }
    }
  }
}
template<int E>
__device__ __forceinline__ void reg_tail(unsigned long long* key, int t, int k2, int jstart){
  if constexpr (E>=8) { if (jstart>=4) reg_step<E,4>(key,t,k2); }
  if constexpr (E>=4) { if (jstart>=2) reg_step<E,2>(key,t,k2); }
  if (jstart>=1) reg_step<E,1>(key,t,k2);
}
template<int E>
__device__ void bitonic_desc(unsigned long long* key, unsigned long long* lds){
  const int t = threadIdx.x;
  const int N = E*256;
  for (int k2=2;k2<=N;k2<<=1){
    for (int j=k2>>1; j>=E; j>>=1){
      int w = j/E;
      bool lower = ((t & w)==0);
      bool desc  = (((t*E) & k2)==0);
      bool keep_max = (desc == lower);
      if (w < 64){
        #pragma unroll
        for (int r=0;r<E;r++){
          unsigned long long mine=key[r];
          unsigned long long o=shfl_xor_u64(mine, w);
          bool gt = mine > o;
          key[r] = keep_max ? (gt?mine:o) : (gt?o:mine);
        }
      } else {
        __syncthreads();
        #pragma unroll
        for (int r=0;r<E;r++) lds[t*E+r]=key[r];
        __syncthreads();
        #pragma unroll
        for (int r=0;r<E;r++){
          unsigned long long mine=key[r];
          unsigned long long o=lds[(t*E+r)^j];
          bool gt = mine > o;
          key[r] = keep_max ? (gt?mine:o) : (gt?o:mine);
        }
      }
    }
    int jstart = ((k2>>1) < (E>>1)) ? (k2>>1) : (E>>1);
    reg_tail<E>(key,t,k2,jstart);
  }
  __syncthreads();
  #pragma unroll
  for (int r=0;r<E;r++) lds[t*E+r]=key[r];
  __syncthreads();
}

// ---------------- S1: sort 1024-chunks, keep top-100 ----------------
__global__ __launch_bounds__(256) void k_sel1(
    const float* __restrict__ h0, const float* __restrict__ h1, const float* __restrict__ h2,
    unsigned long long* __restrict__ c1)
{
  int b = blockIdx.x;
  int layer, chunk;
  if (b < 320){ layer=0; chunk=b; }
  else if (b < 400){ layer=1; chunk=b-320; }
  else { layer=2; chunk=b-400; }
  const float* heat = (layer==0)?h0:((layer==1)?h1:h2);
  __shared__ unsigned long long lds[1024];
  unsigned long long key[4];
  int t = threadIdx.x;
  int base = chunk*1024 + t*4;
  float4 v = *(const float4*)(heat + base);
  key[0] = ((unsigned long long)fkey_u(v.x)<<32) | (unsigned long long)(0xFFFFFFFFu - (unsigned)(base+0));
  key[1] = ((unsigned long long)fkey_u(v.y)<<32) | (unsigned long long)(0xFFFFFFFFu - (unsigned)(base+1));
  key[2] = ((unsigned long long)fkey_u(v.z)<<32) | (unsigned long long)(0xFFFFFFFFu - (unsigned)(base+2));
  key[3] = ((unsigned long long)fkey_u(v.w)<<32) | (unsigned long long)(0xFFFFFFFFu - (unsigned)(base+3));
  bitonic_desc<4>(key, lds);
  if (t<100) c1[(size_t)b*100 + t] = lds[t];
}

// ---------------- S2: merge 20 sorted lists -> top-100 ----------------
__global__ __launch_bounds__(256) void k_sel2(
    const unsigned long long* __restrict__ c1, unsigned long long* __restrict__ c2)
{
  int b = blockIdx.x;
  __shared__ unsigned long long lds[2048];
  unsigned long long key[8];
  int t=threadIdx.x;
  const unsigned long long* src = c1 + (size_t)b*2000;
  #pragma unroll
  for (int r=0;r<8;r++){
    int i=t*8+r;
    key[r] = (i<2000)? src[i] : 0ull;
  }
  bitonic_desc<8>(key, lds);
  if (t<100) c2[(size_t)b*100+t]=lds[t];
}

// ---------------- S3: final merge per layer + decode ----------------
__global__ __launch_bounds__(256) void k_sel3_decode(
    const unsigned long long* __restrict__ c2,
    const float* __restrict__ tl0,const float* __restrict__ tl1,const float* __restrict__ tl2,
    const float* __restrict__ br0,const float* __restrict__ br1,const float* __restrict__ br2,
    float* __restrict__ dets, float* __restrict__ bws, float* __restrict__ mbw)
{
  int layer = blockIdx.x;
  int hw = 4096 >> (layer*2);
  int W = 64>>layer;
  float Wf = (float)W;
  const float* tl = (layer==0)?tl0:((layer==1)?tl1:tl2);
  const float* br = (layer==0)?br0:((layer==1)?br1:br2);
  int base = (layer==0)?0:((layer==1)?1600:2000);
  int cnt  = (layer==0)?1600:((layer==1)?400:100);
  __shared__ unsigned long long lds[2048];
  __shared__ float scl[100];
  unsigned long long key[8];
  int t = threadIdx.x;
  #pragma unroll
  for (int r=0;r<8;r++){
    int i=t*8+r;
    key[r] = (i<cnt)? c2[base+i] : 0ull;
  }
  bitonic_desc<8>(key, lds);
  unsigned long long kwin=0;
  if (t<100) kwin = lds[t];
  float tlx=0,tly=0,brx=0,bry=0,xs=0,ys=0,clsfv=0,scv=0;
  if (t<100){
    unsigned m=(unsigned)(kwin>>32);
    unsigned gidx = 0xFFFFFFFFu - (unsigned)(kwin & 0xFFFFFFFFull);
    float val = fkey_inv(m);
    int cls = (int)(gidx / (unsigned)hw);
    int rem = (int)(gidx % (unsigned)hw);
    int iy = rem / W, ix = rem % W;
    xs = (float)ix; ys = (float)iy; clsfv = (float)cls;
    float t0=tl[rem], t1=tl[hw+rem], b0=br[rem], b1=br[hw+rem];
    tlx = fminf(fmaxf(xs - (3.0f*t0 + 2.5f), 0.0f), Wf);
    tly = fminf(fmaxf(ys - (3.0f*t1 + 2.5f), 0.0f), Wf);
    brx = fminf(fmaxf(xs + (3.0f*b0 + 2.5f), 0.0f), Wf);
    bry = fminf(fmaxf(ys + (3.0f*b1 + 2.5f), 0.0f), Wf);
    scv = ((brx<tlx)||(bry<tly)) ? -1.0f : val;
    scl[t]=scv;
  }
  __syncthreads();
  if (t<100){
    int rank=0;
    for (int i=0;i<100;i++){
      float si=scl[i];
      rank += ((si>scv)||(si==scv && i<t)) ? 1 : 0;
    }
    int row = layer*100 + rank;
    float sx = (float)(1<<layer);
    float* dr = dets + row*8;
    dr[0]=tlx*sx; dr[1]=tly*sx; dr[2]=brx*sx; dr[3]=bry*sx;
    dr[4]=scv; dr[5]=scv; dr[6]=(float)layer; dr[7]=clsfv;
    float* bwr = bws + row*8;
    bwr[0]=tlx;bwr[1]=tly;bwr[2]=brx;bwr[3]=bry;bwr[4]=scv;bwr[5]=scv;bwr[6]=(float)layer;bwr[7]=clsfv;
    float* mr = mbw + row*5;
    mr[0]=xs-4.0f; mr[1]=ys-4.0f; mr[2]=xs+4.0f; mr[3]=ys+4.0f; mr[4]=(float)layer;
  }
}

// ---------------- K_C: NMS — rank-space masks + single-thread register scan ----------------
#define SCAN_GROUP(SW, BASE, CNT) \
  _Pragma("unroll 4") \
  for (int rr=0; rr<CNT; rr++){ \
    int r = BASE+rr; \
    unsigned long long w0=sm[r][0],w1=sm[r][1],w2=sm[r][2],w3=sm[r][3],w4=sm[r][4]; \
    unsigned long long kq = (~(SW>>rr))&1ull; \
    keepr[r]=(unsigned char)kq; \
    unsigned long long msk = 0ull - kq; \
    s0|=w0&msk; s1|=w1&msk; s2|=w2&msk; s3|=w3&msk; s4|=w4&msk; \
  }

__global__ __launch_bounds__(320) void k_nms(
    const float* __restrict__ dets, const float* __restrict__ bws, const float* __restrict__ mbw,
    float* __restrict__ out_dets, float* __restrict__ mbf, int* __restrict__ clsf,
    int* __restrict__ layf, float* __restrict__ nbox)
{
  __shared__ __align__(16) float4 rb[300];
  __shared__ float rs[300];
  __shared__ int orig[300];
  __shared__ __align__(16) float sc[300];
  __shared__ __align__(16) float kk[300];
  __shared__ __align__(16) float lq[300];
  __shared__ float lyv[300];
  __shared__ unsigned long long sm[300][5];
  __shared__ unsigned char keepr[304];
  __shared__ int sel_[300], fperm[300];
  int t = threadIdx.x;
  float X1=0,Y1=0,X2=0,Y2=0,S=0;
  if (t<300){
    const float* r = dets + t*8;
    X1=r[1];Y1=r[2];X2=r[3];Y2=r[4];
    S=r[4];
    sc[t]=S;
    lyv[t]=mbw[t*5+4];
  }
  __syncthreads();
  if (t<300){
    int rank=0;
    for (int j4=0;j4<75;j4++){
      float4 s4=*(const float4*)&sc[j4*4];
      int j=j4*4;
      rank += ((s4.x>S)||(s4.x==S&&(j+0)<t)) ? 1:0;
      rank += ((s4.y>S)||(s4.y==S&&(j+1)<t)) ? 1:0;
      rank += ((s4.z>S)||(s4.z==S&&(j+2)<t)) ? 1:0;
      rank += ((s4.w>S)||(s4.w==S&&(j+3)<t)) ? 1:0;
    }
    rb[rank]=make_float4(X1,Y1,X2,Y2);
    rs[rank]=S;
    orig[rank]=t;
  }
  __syncthreads();
  if (t<300){
    float4 me=rb[t];
    float A=(me.z-me.x)*(me.w-me.y);
    #pragma unroll
    for (int jw=0;jw<5;jw++){
      unsigned long long bits=0;
      int lim=(jw==4)?44:64;
      for (int jj=0;jj<lim;jj++){
        int j=jw*64+jj;
        float4 q=rb[j];
        float aj=(q.z-q.x)*(q.w-q.y);
        float ix1=fmaxf(me.x,q.x), iy1=fmaxf(me.y,q.y);
        float ix2=fminf(me.z,q.z), iy2=fminf(me.w,q.w);
        float it=fmaxf(ix2-ix1,0.f)*fmaxf(iy2-iy1,0.f);
        float iou=it/(A+aj-it+1e-9f);
        bits |= ((unsigned long long)(iou>0.5f))<<jj;
      }
      sm[t][jw]=bits;
    }
  }
  __syncthreads();
  if (t==0){
    unsigned long long s0=0,s1=0,s2=0,s3=0,s4=0;
    SCAN_GROUP(s0,0,64)
    SCAN_GROUP(s1,64,64)
    SCAN_GROUP(s2,128,64)
    SCAN_GROUP(s3,192,64)
    SCAN_GROUP(s4,256,44)
  }
  __syncthreads();
  if (t<300) kk[orig[t]] = keepr[t] ? rs[t] : -1000000000.0f;
  __syncthreads();
  float KV=0; int rank2=0;
  if (t<300){
    KV=kk[t];
    for (int j4=0;j4<75;j4++){
      float4 s4=*(const float4*)&kk[j4*4];
      int j=j4*4;
      rank2 += ((s4.x>KV)||(s4.x==KV&&(j+0)<t)) ? 1:0;
      rank2 += ((s4.y>KV)||(s4.y==KV&&(j+1)<t)) ? 1:0;
      rank2 += ((s4.z>KV)||(s4.z==KV&&(j+2)<t)) ? 1:0;
      rank2 += ((s4.w>KV)||(s4.w==KV&&(j+3)<t)) ? 1:0;
    }
    sel_[rank2]=t;
  }
  __syncthreads();
  if (t<300) lq[t]=lyv[sel_[t]];
  __syncthreads();
  if (t<300){
    float L=lq[t]; int rank3=0;
    for (int j4=0;j4<75;j4++){
      float4 s4=*(const float4*)&lq[j4*4];
      int j=j4*4;
      rank3 += ((s4.x>L)||(s4.x==L&&(j+0)<t)) ? 1:0;
      rank3 += ((s4.y>L)||(s4.y==L&&(j+1)<t)) ? 1:0;
      rank3 += ((s4.z>L)||(s4.z==L&&(j+2)<t)) ? 1:0;
      rank3 += ((s4.w>L)||(s4.w==L&&(j+3)<t)) ? 1:0;
    }
    fperm[rank3]=sel_[t];
  }
  __syncthreads();
  if (t<300){
    int src=fperm[t];
    const float* dr=dets+src*8;
    #pragma unroll
    for (int c=0;c<8;c++) out_dets[t*8+c]=dr[c];
    const float* mr=mbw+src*5;
    #pragma unroll
    for (int c=0;c<5;c++) mbf[t*5+c]=mr[c];
    int cc=(int)dr[7]; cc = cc<0?0:(cc>79?79:cc); clsf[t]=cc;
    int lv=(int)mr[4]; lv = lv<0?0:(lv>2?2:lv); layf[t]=lv;
    const float* bw=bws+src*8;
    nbox[t*4+0]=4.375f*(bw[0]-mr[0]);
    nbox[t*4+1]=4.375f*(bw[1]-mr[1]);
    nbox[t*4+2]=4.375f*(bw[2]-mr[0]);
    nbox[t*4+3]=4.375f*(bw[3]-mr[1]);
  }
}

// ---------------- ROI align -> bf16 [px][ci] ----------------
__global__ __launch_bounds__(256) void k_roi(
    const float* __restrict__ f0,const float* __restrict__ f1,const float* __restrict__ f2,
    const float* __restrict__ mbf, const int* __restrict__ layf,
    unsigned short* __restrict__ rois, int r0)
{
  int nl = blockIdx.x; int g = r0 + nl;
  __shared__ int ix0[9], ix1[9], iy0[9], iy1[9];
  __shared__ float wx[9], wy[9];
  int lay = layf[g];
  int W = 64>>lay;
  float Wf1 = (float)(W-1);
  const float* feat = (lay==0)?f0:((lay==1)?f1:f2);
  int t=threadIdx.x;
  if (t<9){
    float x1=mbf[g*5+0], x2=mbf[g*5+2];
    float jx = ((float)t + 0.5f)/9.0f;
    float gx = x1 + (x2-x1)*jx;
    float xx = fminf(fmaxf(gx,0.0f), Wf1);
    float x0f = floorf(xx);
    wx[t]=xx-x0f;
    int x0=(int)x0f; ix0[t]=x0; ix1[t]=min(x0+1,W-1);
  } else if (t>=16 && t<25){
    int j=t-16;
    float y1=mbf[g*5+1], y2=mbf[g*5+3];
    float jy=((float)j+0.5f)/9.0f;
    float gy=y1+(y2-y1)*jy;
    float yy=fminf(fmaxf(gy,0.0f),Wf1);
    float y0f=floorf(yy);
    wy[j]=yy-y0f;
    int y0=(int)y0f; iy0[j]=y0; iy1[j]=min(y0+1,W-1);
  }
  __syncthreads();
  int c=t;
  const float* fp = feat + (size_t)c*W*W;
  unsigned short* op = rois + (size_t)nl*81*256;
  for (int p=0;p<81;p++){
    int py=p/9, px=p%9;
    float v00=fp[iy0[py]*W+ix0[px]];
    float v01=fp[iy0[py]*W+ix1[px]];
    float v10=fp[iy1[py]*W+ix0[px]];
    float v11=fp[iy1[py]*W+ix1[px]];
    float wxx=wx[px], wyy=wy[py];
    float v = (1.0f-wyy)*((1.0f-wxx)*v00 + wxx*v01) + wyy*((1.0f-wxx)*v10 + wxx*v11);
    op[(size_t)p*256 + c] = f2bf(v);
  }
}

// ---------------- weight prep ----------------
__global__ __launch_bounds__(64) void k_wprep3(
    const float* __restrict__ c1w, const float* __restrict__ midw, const float* __restrict__ c5w,
    unsigned short* __restrict__ WB)
{
  int b = blockIdx.x, c = blockIdx.y, l = threadIdx.x;
  int t = b>>7;
  const float* src = (c==0)? c1w : (c<=3 ? midw + (size_t)(c-1)*589824 : c5w);
  unsigned short* dst = WB + (size_t)c*589824 + ((size_t)b<<9) + l*8;
  int co = (b&15)*16 + (l&15);
  int cib = ((b>>4)&7)*32 + ((l>>4)<<3);
  #pragma unroll
  for (int j=0;j<8;j++) dst[j] = f2bf(src[((size_t)co*256 + cib + j)*9 + t]);
}
__global__ __launch_bounds__(64) void k_wprep2(
    const float* __restrict__ d1w, const float* __restrict__ d2w,
    unsigned short* __restrict__ WD)
{
  int b = blockIdx.x, c = blockIdx.y, l = threadIdx.x;
  int t = b>>7;
  const float* src = (c==0)? d1w : d2w;
  unsigned short* dst = WD + (size_t)c*262144 + ((size_t)b<<9) + l*8;
  int co = (b&15)*16 + (l&15);
  int cib = ((b>>4)&7)*32 + ((l>>4)<<3);
  #pragma unroll
  for (int j=0;j<8;j++) dst[j] = f2bf(src[((size_t)co*256 + cib + j)*4 + t]);
}

// ---------------- MFMA conv3x3 @ 9x9, M-split halves ----------------
__global__ __launch_bounds__(256,3) void k_mconv9h(
    const unsigned short* __restrict__ Xg, unsigned short* __restrict__ Yg,
    const unsigned short* __restrict__ WBc,
    const float* __restrict__ Bc, const float* __restrict__ Gg, const float* __restrict__ Bn)
{
  __shared__ __align__(16) unsigned short Xp[88*264];
  int tid=threadIdx.x, l=tid&63, w=tid>>6;
  int h=blockIdx.y;
  int rlo = h ? 4 : -1;
  const unsigned short* Xr = Xg + (size_t)blockIdx.x*81*256;
  for (int idx=tid; idx<88*32; idx+=256){
    int pp=idx>>5, k8=idx&31;
    int y=pp/11 + rlo, x=pp%11 - 1;
    uint4 v{0,0,0,0};
    if ((unsigned)y<9u && (unsigned)x<9u) v = *(const uint4*)(Xr + ((y*9+x)<<8) + (k8<<3));
    *(uint4*)&Xp[pp*264 + (k8<<3)] = v;
  }
  __syncthreads();
  int mbase = h*48;
  int pixb[3];
  #pragma unroll
  for (int mt=0;mt<3;mt++){
    int m=mbase+mt*16+(l&15); if(m>80)m=80;
    pixb[mt]=(m/9 - rlo)*11 + (m%9) + 1;
  }
  int kg=(l>>4)<<3;
  f32x4 acc[3][4] = {};
  const unsigned short* wbase = WBc + (size_t)l*8;
  for (int t9=0;t9<9;t9++){
    int toff=(t9/3-1)*11 + (t9%3-1);
    for (int kc=0;kc<8;kc++){
      bf16x8 a[3], b[4];
      #pragma unroll
      for (int mt=0;mt<3;mt++) a[mt] = *(const bf16x8*)&Xp[(pixb[mt]+toff)*264 + (kc<<5) + kg];
      #pragma unroll
      for (int nn=0;nn<4;nn++) b[nn] = *(const bf16x8*)(wbase + ((size_t)(((t9<<3)+kc)*16 + (w<<2)+nn)<<9));
      #pragma unroll
      for (int mt=0;mt<3;mt++){
        #pragma unroll
        for (int nn=0;nn<4;nn++)
          acc[mt][nn] = __builtin_amdgcn_mfma_f32_16x16x32_bf16(a[mt], b[nn], acc[mt][nn], 0,0,0);
      }
    }
  }
  unsigned short* Yr = Yg + (size_t)blockIdx.x*81*256;
  int rb=(l>>4)<<2;
  #pragma unroll
  for (int nn=0;nn<4;nn++){
    int co=(w<<6)+(nn<<4)+(l&15);
    float bc=Bc[co], gm=Gg[co]*BNI, bb=Bn[co];
    #pragma unroll
    for (int mt=0;mt<3;mt++){
      #pragma unroll
      for (int r=0;r<4;r++){
        int m=mbase+mt*16+rb+r;
        if (m<81){
          float v=fmaxf((acc[mt][nn][r]+bc)*gm+bb, 0.f);
          Yr[m*256+co]=f2bf(v);
        }
      }
    }
  }
}

// ---------------- MFMA deconv1 (9->18), all 4 taps in one block ----------------
__global__ __launch_bounds__(256,3) void k_mdeconv1(
    const unsigned short* __restrict__ Xg, unsigned short* __restrict__ Yg,
    const unsigned short* __restrict__ WD1, const float* __restrict__ Bd)
{
  __shared__ __align__(16) unsigned short Xp[81*264];
  int tid=threadIdx.x, l=tid&63, w=tid>>6;
  const unsigned short* Xr = Xg + (size_t)blockIdx.x*81*256;
  for (int idx=tid; idx<81*32; idx+=256){
    int pp=idx>>5, k8=idx&31;
    *(uint4*)&Xp[pp*264+(k8<<3)] = *(const uint4*)(Xr + (pp<<8)+(k8<<3));
  }
  __syncthreads();
  int pixb[6];
  #pragma unroll
  for (int mt=0;mt<6;mt++){ int m=mt*16+(l&15); pixb[mt]=(m>80)?80:m; }
  int kg=(l>>4)<<3;
  int rb=(l>>4)<<2;
  unsigned short* Yr = Yg + (size_t)blockIdx.x*324*256;
  for (int tp=0;tp<4;tp++){
    f32x4 acc[6][4] = {};
    const unsigned short* wbase = WD1 + (size_t)tp*65536 + (size_t)l*8;
    for (int kc=0;kc<8;kc++){
      bf16x8 a[6], b[4];
      #pragma unroll
      for (int mt=0;mt<6;mt++) a[mt] = *(const bf16x8*)&Xp[pixb[mt]*264 + (kc<<5) + kg];
      #pragma unroll
      for (int nn=0;nn<4;nn++) b[nn] = *(const bf16x8*)(wbase + ((size_t)(kc*16 + (w<<2)+nn)<<9));
      #pragma unroll
      for (int mt=0;mt<6;mt++){
        #pragma unroll
        for (int nn=0;nn<4;nn++)
          acc[mt][nn] = __builtin_amdgcn_mfma_f32_16x16x32_bf16(a[mt], b[nn], acc[mt][nn], 0,0,0);
      }
    }
    int ky=tp>>1, kx=tp&1;
    #pragma unroll
    for (int nn=0;nn<4;nn++){
      int co=(w<<6)+(nn<<4)+(l&15);
      float bd=Bd[co];
      #pragma unroll
      for (int mt=0;mt<6;mt++){
        #pragma unroll
        for (int r=0;r<4;r++){
          int m=mt*16+rb+r;
          if (m<81){
            int iy=m/9, ix=m%9;
            int opx=(2*iy+1-ky)*18 + (2*ix+1-kx);
            Yr[opx*256+co]=f2bf(fmaxf(acc[mt][nn][r]+bd,0.f));
          }
        }
      }
    }
  }
}

// ---------------- MFMA conv3x3 @ 18x18 + bias + BN + ReLU (co-split, nn=2) ----------------
__global__ __launch_bounds__(256,3) void k_mconv18(
    const unsigned short* __restrict__ Xg, unsigned short* __restrict__ Yg,
    const unsigned short* __restrict__ WBc,
    const float* __restrict__ Bc, const float* __restrict__ Gg, const float* __restrict__ Bn)
{
  __shared__ __align__(16) unsigned short Xp[160*136];
  int tid=threadIdx.x, l=tid&63, w=tid>>6;
  int rg=blockIdx.y, ch=blockIdx.z;
  const unsigned short* Xr = Xg + (size_t)blockIdx.x*324*256;
  int pixb[7];
  #pragma unroll
  for (int mt=0;mt<7;mt++){ int m=mt*16+(l&15); if(m>107)m=107; pixb[mt]=(m/18)*20+(m%18); }
  int kg=(l>>4)<<3;
  f32x4 acc[7][2] = {};
  const unsigned short* wbase = WBc + (size_t)l*8;
  for (int h=0;h<2;h++){
    __syncthreads();
    for (int idx=tid; idx<160*16; idx+=256){
      int pp=idx>>4, k8=idx&15;
      int py=rg*6-1+pp/20, px=pp%20-1;
      uint4 v{0,0,0,0};
      if ((unsigned)py<18u && (unsigned)px<18u)
        v = *(const uint4*)(Xr + ((py*18+px)<<8) + (h<<7) + (k8<<3));
      *(uint4*)&Xp[pp*136 + (k8<<3)] = v;
    }
    __syncthreads();
    for (int t9=0;t9<9;t9++){
      int toff=(t9/3)*20 + (t9%3);
      for (int kc=0;kc<4;kc++){
        int kcg=(h<<2)+kc;
        bf16x8 a[7], b[2];
        #pragma unroll
        for (int mt=0;mt<7;mt++) a[mt] = *(const bf16x8*)&Xp[(pixb[mt]+toff)*136 + (kc<<5) + kg];
        #pragma unroll
        for (int nn=0;nn<2;nn++) b[nn] = *(const bf16x8*)(wbase + ((size_t)(((t9<<3)+kcg)*16 + (ch<<3)+(w<<1)+nn)<<9));
        #pragma unroll
        for (int mt=0;mt<7;mt++){
          #pragma unroll
          for (int nn=0;nn<2;nn++)
            acc[mt][nn] = __builtin_amdgcn_mfma_f32_16x16x32_bf16(a[mt], b[nn], acc[mt][nn], 0,0,0);
        }
      }
    }
  }
  unsigned short* Yr = Yg + (size_t)blockIdx.x*324*256;
  int rb=(l>>4)<<2;
  #pragma unroll
  for (int nn=0;nn<2;nn++){
    int co=(ch<<7)+(w<<5)+(nn<<4)+(l&15);
    float bc=Bc[co], gm=Gg[co]*BNI, bb=Bn[co];
    #pragma unroll
    for (int mt=0;mt<7;mt++){
      #pragma unroll
      for (int r=0;r<4;r++){
        int m=mt*16+rb+r;
        if (m<108){
          int opx=rg*108+m;
          Yr[opx*256+co]=f2bf(fmaxf((acc[mt][nn][r]+bc)*gm+bb, 0.f));
        }
      }
    }
  }
}

// ---------------- MFMA deconv2 (18->36) + ReLU + c6[cls] + sigmoid, 4 taps/block --------
__global__ __launch_bounds__(256,2) void k_mdec2c6(
    const unsigned short* __restrict__ Xg,
    const unsigned short* __restrict__ WD2, const float* __restrict__ Bd,
    const float* __restrict__ W6, const float* __restrict__ B6,
    const int* __restrict__ clsf, float* __restrict__ mask36, int r0)
{
  __shared__ __align__(16) unsigned short Xp[108*264];
  __shared__ float part[4][112];
  int tid=threadIdx.x, l=tid&63, w=tid>>6;
  int rg=blockIdx.y;
  int g=r0+blockIdx.x;
  const unsigned short* Xr = Xg + (size_t)blockIdx.x*324*256 + (size_t)rg*108*256;
  for (int idx=tid; idx<108*32; idx+=256){
    int pp=idx>>5, k8=idx&31;
    *(uint4*)&Xp[pp*264+(k8<<3)] = *(const uint4*)(Xr + (pp<<8)+(k8<<3));
  }
  __syncthreads();
  int pixb[7];
  #pragma unroll
  for (int mt=0;mt<7;mt++){ int m=mt*16+(l&15); pixb[mt]=(m>107)?107:m; }
  int kg=(l>>4)<<3;
  int rb=(l>>4)<<2;
  int cls=clsf[g];
  float w6v[4], bdv[4];
  #pragma unroll
  for (int nn=0;nn<4;nn++){
    int co=(w<<6)+(nn<<4)+(l&15);
    w6v[nn]=W6[(size_t)cls*256+co];
    bdv[nn]=Bd[co];
  }
  float b6c=B6[cls];
  for (int tp=0;tp<4;tp++){
    f32x4 acc[7][4] = {};
    const unsigned short* wbase = WD2 + (size_t)tp*65536 + (size_t)l*8;
    for (int kc=0;kc<8;kc++){
      bf16x8 a[7], b[4];
      #pragma unroll
      for (int mt=0;mt<7;mt++) a[mt] = *(const bf16x8*)&Xp[pixb[mt]*264 + (kc<<5) + kg];
      #pragma unroll
      for (int nn=0;nn<4;nn++) b[nn] = *(const bf16x8*)(wbase + ((size_t)(kc*16 + (w<<2)+nn)<<9));
      #pragma unroll
      for (int mt=0;mt<7;mt++){
        #pragma unroll
        for (int nn=0;nn<4;nn++)
          acc[mt][nn] = __builtin_amdgcn_mfma_f32_16x16x32_bf16(a[mt], b[nn], acc[mt][nn], 0,0,0);
      }
    }
    #pragma unroll
    for (int mt=0;mt<7;mt++){
      float s0=0.f,s1=0.f,s2=0.f,s3=0.f;
      #pragma unroll
      for (int nn=0;nn<4;nn++){
        s0 += fmaxf(acc[mt][nn][0]+bdv[nn],0.f)*w6v[nn];
        s1 += fmaxf(acc[mt][nn][1]+bdv[nn],0.f)*w6v[nn];
        s2 += fmaxf(acc[mt][nn][2]+bdv[nn],0.f)*w6v[nn];
        s3 += fmaxf(acc[mt][nn][3]+bdv[nn],0.f)*w6v[nn];
      }
      #pragma unroll
      for (int o=1;o<16;o<<=1){
        s0 += __shfl_xor(s0,o,64);
        s1 += __shfl_xor(s1,o,64);
        s2 += __shfl_xor(s2,o,64);
        s3 += __shfl_xor(s3,o,64);
      }
      if ((l&15)==0){
        int mb=mt*16+rb;
        part[w][mb+0]=s0; part[w][mb+1]=s1; part[w][mb+2]=s2; part[w][mb+3]=s3;
      }
    }
    __syncthreads();
    if (tid<108){
      float lg = part[0][tid]+part[1][tid]+part[2][tid]+part[3][tid] + b6c;
      int pg=rg*108+tid, iy=pg/18, ix=pg%18;
      int ky=tp>>1, kx=tp&1;
      mask36[(size_t)g*1296 + (2*iy+1-ky)*36 + (2*ix+1-kx)] = 1.0f/(1.0f+expf(-lg));
    }
    __syncthreads();
  }
}

// ---------------- crop_resize 36x36 -> 36x36 ----------------
__global__ __launch_bounds__(256) void k_crop(
    const float* __restrict__ mask36, const float* __restrict__ nbox,
    float* __restrict__ outm)
{
  int r=blockIdx.x;
  __shared__ float m[1296];
  int t=threadIdx.x;
  for (int i=t;i<1296;i+=256) m[i]=mask36[(size_t)r*1296+i];
  float x1=nbox[r*4+0], y1=nbox[r*4+1], x2=nbox[r*4+2], y2=nbox[r*4+3];
  __syncthreads();
  for (int p=t;p<1296;p+=256){
    int oy=p/36, ox=p%36;
    float tx=(float)ox/35.0f, ty=(float)oy/35.0f;
    float gx=x1+(x2-x1)*tx, gy=y1+(y2-y1)*ty;
    float xx=fminf(fmaxf(gx,0.f),35.0f), yy=fminf(fmaxf(gy,0.f),35.0f);
    float x0f=floorf(xx), y0f=floorf(yy);
    float wxv=xx-x0f, wyv=yy-y0f;
    int x0=(int)x0f, y0=(int)y0f;
    int x1i=min(x0+1,35), y1i=min(y0+1,35);
    float v00=m[y0*36+x0], v01=m[y0*36+x1i], v10=m[y1i*36+x0], v11=m[y1i*36+x1i];
    outm[(size_t)r*1296+p]=(1.f-wyv)*((1.f-wxv)*v00+wxv*v01)+wyv*((1.f-wxv)*v10+wxv*v11);
  }
}

// ---------------- host ----------------
extern "C" void kernel_launch(void* const* d_in, const int* in_sizes, int n_in,
                              void* d_out, int out_size, void* d_ws, size_t ws_size,
                              hipStream_t stream) {
  int iH[3], iT[3], iB[3], iF[3];
  if (n_in >= 12 && in_sizes[1] == 2*64*64) {
    for (int l=0;l<3;l++){ iH[l]=l*4+0; iT[l]=l*4+1; iB[l]=l*4+2; iF[l]=l*4+3; }
  } else {
    for (int l=0;l<3;l++){ iH[l]=l; iT[l]=3+l; iB[l]=6+l; iF[l]=9+l; }
  }
  const float* heat0=(const float*)d_in[iH[0]];
  const float* heat1=(const float*)d_in[iH[1]];
  const float* heat2=(const float*)d_in[iH[2]];
  const float* tl0=(const float*)d_in[iT[0]];
  const float* tl1=(const float*)d_in[iT[1]];
  const float* tl2=(const float*)d_in[iT[2]];
  const float* br0=(const float*)d_in[iB[0]];
  const float* br1=(const float*)d_in[iB[1]];
  const float* br2=(const float*)d_in[iB[2]];
  const float* feat0=(const float*)d_in[iF[0]];
  const float* feat1=(const float*)d_in[iF[1]];
  const float* feat2=(const float*)d_in[iF[2]];
  const float* c1w=(const float*)d_in[12];
  const float* c1b=(const float*)d_in[13];
  const float* midw=(const float*)d_in[14];
  const float* midb=(const float*)d_in[15];
  const float* bng=(const float*)d_in[16];
  const float* bnb=(const float*)d_in[17];
  const float* d1w=(const float*)d_in[18];
  const float* d1b=(const float*)d_in[19];
  const float* d2w=(const float*)d_in[20];
  const float* d2b=(const float*)d_in[21];
  const float* c5w=(const float*)d_in[22];
  const float* c5b=(const float*)d_in[23];
  const float* c6w=(const float*)d_in[24];
  const float* c6b=(const float*)d_in[25];
  float* out=(float*)d_out;

  char* ws=(char*)d_ws;
  size_t cur=0;
  auto alloc=[&](size_t bytes)->char*{
    char* p=ws+cur;
    cur=(cur+bytes+255)&~(size_t)255;
    return p;
  };
  unsigned short* WB=(unsigned short*)alloc(5ull*589824*2);
  unsigned short* WD=(unsigned short*)alloc(2ull*262144*2);
  unsigned long long* c1s=(unsigned long long*)alloc(420ull*100*8);
  unsigned long long* c2s=(unsigned long long*)alloc(21ull*100*8);
  float* detsw=(float*)alloc(300*8*4);
  float* bwsw=(float*)alloc(300*8*4);
  float* mbw=(float*)alloc(300*5*4);
  float* mbf=(float*)alloc(300*5*4);
  int* clsf=(int*)alloc(300*4);
  int* layf=(int*)alloc(300*4);
  float* nbox=(float*)alloc(300*4*4);
  float* mask36=(float*)alloc(300ull*1296*4);
  size_t fixed=cur;
  size_t perroi = (size_t)(2*81 + 2*324)*256*2;
  size_t avail = (ws_size>fixed+4096)? (ws_size-fixed-4096):0;
  int NRC = (int)(avail/perroi);
  if (NRC>300) NRC=300;
  if (NRC<1) NRC=1;
  unsigned short* X0 =(unsigned short*)alloc((size_t)NRC*81*256*2);
  unsigned short* B9 =(unsigned short*)alloc((size_t)NRC*81*256*2);
  unsigned short* C18=(unsigned short*)alloc((size_t)NRC*324*256*2);
  unsigned short* D18=(unsigned short*)alloc((size_t)NRC*324*256*2);

  k_wprep3<<<dim3(1152,5),dim3(64),0,stream>>>(c1w,midw,c5w,WB);
  k_wprep2<<<dim3(512,2),dim3(64),0,stream>>>(d1w,d2w,WD);

  k_sel1<<<dim3(420),dim3(256),0,stream>>>(heat0,heat1,heat2,c1s);
  k_sel2<<<dim3(21),dim3(256),0,stream>>>(c1s,c2s);
  k_sel3_decode<<<dim3(3),dim3(256),0,stream>>>(c2s,tl0,tl1,tl2,br0,br1,br2,detsw,bwsw,mbw);
  k_nms<<<dim3(1),dim3(320),0,stream>>>(detsw,bwsw,mbw,out,mbf,clsf,layf,nbox);

  for (int r0=0;r0<300;r0+=NRC){
    int nr = (300-r0 < NRC)? (300-r0) : NRC;
    k_roi<<<dim3(nr),dim3(256),0,stream>>>(feat0,feat1,feat2,mbf,layf,X0,r0);
    k_mconv9h<<<dim3(nr,2),dim3(256),0,stream>>>(X0,B9,WB,               c1b,       bng,      bnb);
    k_mconv9h<<<dim3(nr,2),dim3(256),0,stream>>>(B9,X0,WB+1ull*589824,   midb,      bng+256,  bnb+256);
    k_mconv9h<<<dim3(nr,2),dim3(256),0,stream>>>(X0,B9,WB+2ull*589824,   midb+256,  bng+512,  bnb+512);
    k_mconv9h<<<dim3(nr,2),dim3(256),0,stream>>>(B9,X0,WB+3ull*589824,   midb+512,  bng+768,  bnb+768);
    k_mdeconv1<<<dim3(nr),dim3(256),0,stream>>>(X0,C18,WD,d1b);
    k_mconv18<<<dim3(nr,3,2),dim3(256),0,stream>>>(C18,D18,WB+4ull*589824, c5b, bng+1024, bnb+1024);
    k_mdec2c6<<<dim3(nr,3),dim3(256),0,stream>>>(D18,WD+262144,d2b,c6w,c6b,clsf,mask36,r0);
  }
  k_crop<<<dim3(300),dim3(256),0,stream>>>(mask36,nbox,out+2400);
}